// Round 6
// baseline (624.935 us; speedup 1.0000x reference)
//
#include <hip/hip_runtime.h>

#define MIN_VAL 1e-8f
#define SENT    1e10f   // invalid-target sentinel: d ~ 1e20 dominates any valid d
#define ACCINIT 1e30f

constexpr int P     = 256;   // bins per sample (bins input is [N, P+1])
constexpr int BLOCK = 256;
constexpr int CHUNK = 512;   // targets per block-iteration

// ---------------------------------------------------------------------------
// ws layout (no init needed — every word is written before it is read):
//   res      : N doubles          (written by B, read by C)
//   ysum_part: N*CPS doubles      (written by A, read by B)
//   ycnt_part: N*CPS unsigned     (written by A, read by B)
//   binpart  : N*CPS*P floats     (written by A, read by B)
// No atomics, no memsets, no grid.sync — kernel boundaries give coherence.
// ---------------------------------------------------------------------------

__global__ void __launch_bounds__(BLOCK, 4)
chamfer_partial(const float* __restrict__ bins, const float* __restrict__ tgt,
                int M, int C, int CPS,
                double* __restrict__ ysum_part, unsigned* __restrict__ ycnt_part,
                float* __restrict__ binpart) {
    const int n   = blockIdx.y;     // sample
    const int s   = blockIdx.x;     // slice
    const int tid = threadIdx.x;
    const int tg  = tid & 15;       // target-slot lane within 16-group
    const int bg  = tid >> 4;       // bin-group: bins [bg*16, bg*16+16)
    const int w   = tid >> 6;       // wave 0..3
    const int lane = tid & 63;

    __shared__ float  s_bc[P];
    __shared__ float  s_t[CHUNK];
    __shared__ float  s_colw[4][CHUNK + 8];  // per-wave col-min partials
    __shared__ float  s_binmin[P];
    __shared__ double s_red[4];
    __shared__ unsigned s_redc[4];

    // ---- stage bin centers -------------------------------------------------
    const float* bn = bins + (size_t)n * (P + 1);
    s_bc[tid] = 0.5f * (bn[tid] + bn[tid + 1]);
    __syncthreads();
    float bcv[16];
#pragma unroll
    for (int i = 0; i < 16; i += 4) {
        float4 v = *(const float4*)&s_bc[bg * 16 + i];
        bcv[i] = v.x; bcv[i + 1] = v.y; bcv[i + 2] = v.z; bcv[i + 3] = v.w;
    }
    float rmin[16];
#pragma unroll
    for (int i = 0; i < 16; ++i) rmin[i] = ACCINIT;

    double ylocal = 0.0;
    unsigned ycl = 0;
    const float* tp = tgt + (size_t)n * M;

    // ---- strided chunks (CPS == C in the default config: one per block) ----
    for (int c = s; c < C; c += CPS) {
        const int m0 = c * CHUNK;
        float ta = (m0 + tid < M)       ? tp[m0 + tid]       : -1.0f;
        float tb = (m0 + tid + 256 < M) ? tp[m0 + tid + 256] : -1.0f;
        bool va = ta >= MIN_VAL, vb = tb >= MIN_VAL;
        __syncthreads();               // s_t / s_colw reuse guard
        s_t[tid]       = va ? ta : SENT;
        s_t[tid + 256] = vb ? tb : SENT;
        __syncthreads();

        // 4 passes of 16 bins x 8 targets, next-pass targets preloaded
        float4 na = *(const float4*)&s_t[tg * 8];
        float4 nb = *(const float4*)&s_t[tg * 8 + 4];
#pragma unroll 1
        for (int pass = 0; pass < 4; ++pass) {
            float tv[8] = {na.x, na.y, na.z, na.w, nb.x, nb.y, nb.z, nb.w};
            if (pass < 3) {
                na = *(const float4*)&s_t[(pass + 1) * 128 + tg * 8];
                nb = *(const float4*)&s_t[(pass + 1) * 128 + tg * 8 + 4];
            }
            float cmin[8];
#pragma unroll
            for (int j = 0; j < 8; ++j) cmin[j] = ACCINIT;
#pragma unroll
            for (int j = 0; j < 8; ++j) {
                float t = tv[j];
                float cm = cmin[j];
#pragma unroll
                for (int i = 0; i < 16; ++i) {
                    float d = bcv[i] - t;
                    d = d * d;
                    rmin[i] = fminf(rmin[i], d);
                    cm = fminf(cm, d);
                }
                cmin[j] = cm;
            }
            // combine the wave's 4 bin-groups: lanes {l, l^16, l^32, l^48}
#pragma unroll
            for (int j = 0; j < 8; ++j) {
                float cm = cmin[j];
                cm = fminf(cm, __shfl_xor(cm, 16, 64));
                cm = fminf(cm, __shfl_xor(cm, 32, 64));
                cmin[j] = cm;
            }
            if ((tid & 48) == 0) {    // lanes 0-15 of each wave
                float* cp = &s_colw[w][pass * 128 + tg * 8];
                *(float4*)cp       = make_float4(cmin[0], cmin[1], cmin[2], cmin[3]);
                *(float4*)(cp + 4) = make_float4(cmin[4], cmin[5], cmin[6], cmin[7]);
            }
        }
        __syncthreads();

        // per-target min over all 256 bins (4 wave-partials)
        float c0 = fminf(fminf(s_colw[0][tid], s_colw[1][tid]),
                         fminf(s_colw[2][tid], s_colw[3][tid]));
        float c1 = fminf(fminf(s_colw[0][tid + 256], s_colw[1][tid + 256]),
                         fminf(s_colw[2][tid + 256], s_colw[3][tid + 256]));
        ylocal += (va ? (double)c0 : 0.0) + (vb ? (double)c1 : 0.0);
        ycl    += (unsigned)va + (unsigned)vb;
    }

    // ---- per-bin mins -> s_binmin ------------------------------------------
#pragma unroll
    for (int i = 0; i < 16; ++i) {
        float r = rmin[i];
        r = fminf(r, __shfl_down(r, 8, 16));
        r = fminf(r, __shfl_down(r, 4, 16));
        r = fminf(r, __shfl_down(r, 2, 16));
        r = fminf(r, __shfl_down(r, 1, 16));
        rmin[i] = r;
    }
    if (tg == 0) {
#pragma unroll
        for (int i = 0; i < 16; i += 4)
            *(float4*)&s_binmin[bg * 16 + i] =
                make_float4(rmin[i], rmin[i + 1], rmin[i + 2], rmin[i + 3]);
    }

    // ---- block-reduce cham_y partials --------------------------------------
    for (int off = 32; off > 0; off >>= 1) {
        ylocal += __shfl_down(ylocal, off, 64);
        ycl    += __shfl_down(ycl, off, 64);
    }
    if (lane == 0) { s_red[w] = ylocal; s_redc[w] = ycl; }
    __syncthreads();

    // ---- plain coalesced stores of this block's partials -------------------
    binpart[((size_t)n * CPS + s) * P + tid] = s_binmin[tid];
    if (tid == 0) {
        ysum_part[n * CPS + s] = s_red[0] + s_red[1] + s_red[2] + s_red[3];
        ycnt_part[n * CPS + s] = s_redc[0] + s_redc[1] + s_redc[2] + s_redc[3];
    }
}

__global__ void __launch_bounds__(BLOCK)
chamfer_reduce(const double* __restrict__ ysum_part,
               const unsigned* __restrict__ ycnt_part,
               const float* __restrict__ binpart, int CPS,
               double* __restrict__ res) {
    const int nn  = blockIdx.x;
    const int tid = threadIdx.x;
    const int w   = tid >> 6, lane = tid & 63;

    __shared__ double s_sx[4], s_sy[4];
    __shared__ unsigned s_c[4];

    // per-bin min over all slices (thread tid owns bin tid; coalesced reads)
    float acc = ACCINIT;
    const float* bp = binpart + (size_t)nn * CPS * P + tid;
#pragma unroll 4
    for (int c = 0; c < CPS; ++c) acc = fminf(acc, bp[(size_t)c * P]);
    double sx = (double)acc;

    double sy = 0.0; unsigned cnt = 0;
    for (int i = tid; i < CPS; i += BLOCK) {
        sy  += ysum_part[nn * CPS + i];
        cnt += ycnt_part[nn * CPS + i];
    }
    for (int off = 32; off > 0; off >>= 1) {
        sx  += __shfl_down(sx, off, 64);
        sy  += __shfl_down(sy, off, 64);
        cnt += __shfl_down(cnt, off, 64);
    }
    if (lane == 0) { s_sx[w] = sx; s_sy[w] = sy; s_c[w] = cnt; }
    __syncthreads();
    if (tid == 0) {
        double SX = (s_sx[0] + s_sx[1] + s_sx[2] + s_sx[3]) / (double)P;
        double SY = s_sy[0] + s_sy[1] + s_sy[2] + s_sy[3];
        unsigned CC = s_c[0] + s_c[1] + s_c[2] + s_c[3];
        res[nn] = SX + SY / (double)CC;
    }
}

__global__ void chamfer_final(const double* __restrict__ res, int N,
                              float* __restrict__ out) {
    if (threadIdx.x == 0) {
        double tot = 0.0;
        for (int k = 0; k < N; ++k) tot += res[k];
        out[0] = (float)(tot / (double)N);
    }
}

extern "C" void kernel_launch(void* const* d_in, const int* in_sizes, int n_in,
                              void* d_out, int out_size, void* d_ws, size_t ws_size,
                              hipStream_t stream) {
    const float* bins = (const float*)d_in[0];
    const float* tgt  = (const float*)d_in[1];
    float* out = (float*)d_out;

    const int N = in_sizes[0] / (P + 1);      // 8
    const int M = in_sizes[1] / N;            // 65536
    const int C = (M + CHUNK - 1) / CHUNK;    // 128 chunks per sample

    // pick CPS (slices per sample) so the partial buffers fit in ws
    int CPS = C;
    size_t o_res, o_ys, o_yc, o_bp, need;
    for (;;) {
        o_res = 0;
        o_ys  = 64;                                        // N*8 <= 64
        o_yc  = o_ys + (size_t)N * CPS * 8;
        o_bp  = ((o_yc + (size_t)N * CPS * 4 + 63) / 64) * 64;
        need  = o_bp + (size_t)N * CPS * P * 4;
        if (need <= ws_size || CPS == 1) break;
        CPS >>= 1;
    }

    char* ws = (char*)d_ws;
    double*   res     = (double*)(ws + o_res);
    double*   ysum_p  = (double*)(ws + o_ys);
    unsigned* ycnt_p  = (unsigned*)(ws + o_yc);
    float*    binpart = (float*)(ws + o_bp);

    hipLaunchKernelGGL(chamfer_partial, dim3(CPS, N), dim3(BLOCK), 0, stream,
                       bins, tgt, M, C, CPS, ysum_p, ycnt_p, binpart);
    hipLaunchKernelGGL(chamfer_reduce, dim3(N), dim3(BLOCK), 0, stream,
                       ysum_p, ycnt_p, binpart, CPS, res);
    hipLaunchKernelGGL(chamfer_final, dim3(1), dim3(64), 0, stream,
                       res, N, out);
}

// Round 7
// 192.270 us; speedup vs baseline: 3.2503x; 3.2503x over previous
//
#include <hip/hip_runtime.h>

#define MIN_VAL 1e-8f
#define SENT    1e10f   // invalid-target sentinel: d ~ 1e20 dominates any valid d
#define ACCINIT 1e30f

constexpr int P     = 256;   // bins per sample (bins input is [N, P+1])
constexpr int BLOCK = 256;
constexpr int CHUNK = 512;   // targets per block

// ---------------------------------------------------------------------------
// ws layout (no init needed — every word is written before it is read):
//   res      : N doubles          (written by B, read by C)
//   ysum_part: N*CPS doubles      (written by A, read by B)
//   ycnt_part: N*CPS unsigned     (written by A, read by B)
//   binpart  : N*CPS*P floats     (written by A, read by B)
// No atomics, no memsets, no grid.sync — kernel boundaries give coherence.
// ---------------------------------------------------------------------------

__global__ void __launch_bounds__(BLOCK, 4)
chamfer_partial(const float* __restrict__ bins, const float* __restrict__ tgt,
                int M, int C, int CPS,
                double* __restrict__ ysum_part, unsigned* __restrict__ ycnt_part,
                float* __restrict__ binpart) {
    const int n    = blockIdx.y;    // sample
    const int s    = blockIdx.x;    // slice
    const int tid  = threadIdx.x;
    const int tg   = tid & 15;      // target-slot lane within 16-group
    const int bg   = tid >> 4;      // bin-group: bins [bg*16, bg*16+16)
    const int w    = tid >> 6;      // wave 0..3
    const int lane = tid & 63;

    __shared__ float  s_bc[P];
    __shared__ float  s_t[CHUNK];
    __shared__ float  s_colw[4][CHUNK + 8];  // per-wave col-min partials (8.3 KB)
    __shared__ float  s_binmin[P];
    __shared__ double s_red[4];
    __shared__ unsigned s_redc[4];

    // ---- stage bin centers -------------------------------------------------
    const float* bn = bins + (size_t)n * (P + 1);
    s_bc[tid] = 0.5f * (bn[tid] + bn[tid + 1]);
    __syncthreads();
    float bcv[16];
#pragma unroll
    for (int i = 0; i < 16; i += 4) {
        float4 v = *(const float4*)&s_bc[bg * 16 + i];
        bcv[i] = v.x; bcv[i + 1] = v.y; bcv[i + 2] = v.z; bcv[i + 3] = v.w;
    }
    float rmin[16];
#pragma unroll
    for (int i = 0; i < 16; ++i) rmin[i] = ACCINIT;

    double ylocal = 0.0;
    unsigned ycl = 0;
    const float* tp = tgt + (size_t)n * M;

    // ---- strided chunks (CPS == C by default: exactly one per block) -------
    for (int c = s; c < C; c += CPS) {
        const int m0 = c * CHUNK;
        {   // stage targets; invalid -> SENT (validity re-derived from LDS later)
            float ta = (m0 + tid < M)       ? tp[m0 + tid]       : -1.0f;
            float tb = (m0 + tid + 256 < M) ? tp[m0 + tid + 256] : -1.0f;
            __syncthreads();           // s_t / s_colw reuse guard
            s_t[tid]       = (ta >= MIN_VAL) ? ta : SENT;
            s_t[tid + 256] = (tb >= MIN_VAL) ? tb : SENT;
        }
        __syncthreads();

        // ---- 4 passes of 16 bins x 8 targets per thread (R3 spill-free) ----
#pragma unroll 1
        for (int pass = 0; pass < 4; ++pass) {
            const int base = pass * 128 + tg * 8;
            float4 t4a = *(const float4*)&s_t[base];
            float4 t4b = *(const float4*)&s_t[base + 4];
            float tv[8] = {t4a.x, t4a.y, t4a.z, t4a.w, t4b.x, t4b.y, t4b.z, t4b.w};
            float cmin[8];
#pragma unroll
            for (int j = 0; j < 8; ++j) cmin[j] = ACCINIT;
#pragma unroll
            for (int j = 0; j < 8; ++j) {
                float t = tv[j];
                float cm = cmin[j];
#pragma unroll
                for (int i = 0; i < 16; ++i) {
                    float d = bcv[i] - t;
                    d = d * d;
                    rmin[i] = fminf(rmin[i], d);
                    cm = fminf(cm, d);
                }
                cmin[j] = cm;
            }
            // combine the wave's 4 bin-groups: lanes {l, l^16, l^32, l^48}
#pragma unroll
            for (int j = 0; j < 8; ++j) {
                float cm = cmin[j];
                cm = fminf(cm, __shfl_xor(cm, 16, 64));
                cm = fminf(cm, __shfl_xor(cm, 32, 64));
                cmin[j] = cm;
            }
            if ((tid & 48) == 0) {     // lanes 0-15 of each wave
                float* cp = &s_colw[w][base];
                *(float4*)cp       = make_float4(cmin[0], cmin[1], cmin[2], cmin[3]);
                *(float4*)(cp + 4) = make_float4(cmin[4], cmin[5], cmin[6], cmin[7]);
            }
        }
        __syncthreads();

        // ---- per-target min over all 256 bins (4 wave-partials) ------------
        float t0 = s_t[tid], t1 = s_t[tid + 256];
        float c0 = fminf(fminf(s_colw[0][tid], s_colw[1][tid]),
                         fminf(s_colw[2][tid], s_colw[3][tid]));
        float c1 = fminf(fminf(s_colw[0][tid + 256], s_colw[1][tid + 256]),
                         fminf(s_colw[2][tid + 256], s_colw[3][tid + 256]));
        bool va = t0 != SENT, vb = t1 != SENT;
        ylocal += (va ? (double)c0 : 0.0) + (vb ? (double)c1 : 0.0);
        ycl    += (unsigned)va + (unsigned)vb;
    }

    // ---- per-bin mins -> s_binmin ------------------------------------------
#pragma unroll
    for (int i = 0; i < 16; ++i) {
        float r = rmin[i];
        r = fminf(r, __shfl_down(r, 8, 16));
        r = fminf(r, __shfl_down(r, 4, 16));
        r = fminf(r, __shfl_down(r, 2, 16));
        r = fminf(r, __shfl_down(r, 1, 16));
        rmin[i] = r;
    }
    if (tg == 0) {
#pragma unroll
        for (int i = 0; i < 16; i += 4)
            *(float4*)&s_binmin[bg * 16 + i] =
                make_float4(rmin[i], rmin[i + 1], rmin[i + 2], rmin[i + 3]);
    }

    // ---- block-reduce cham_y partials --------------------------------------
    for (int off = 32; off > 0; off >>= 1) {
        ylocal += __shfl_down(ylocal, off, 64);
        ycl    += __shfl_down(ycl, off, 64);
    }
    if (lane == 0) { s_red[w] = ylocal; s_redc[w] = ycl; }
    __syncthreads();

    // ---- plain coalesced stores of this block's partials -------------------
    binpart[((size_t)n * CPS + s) * P + tid] = s_binmin[tid];
    if (tid == 0) {
        ysum_part[n * CPS + s] = s_red[0] + s_red[1] + s_red[2] + s_red[3];
        ycnt_part[n * CPS + s] = s_redc[0] + s_redc[1] + s_redc[2] + s_redc[3];
    }
}

__global__ void __launch_bounds__(BLOCK)
chamfer_reduce(const double* __restrict__ ysum_part,
               const unsigned* __restrict__ ycnt_part,
               const float* __restrict__ binpart, int CPS,
               double* __restrict__ res) {
    const int nn  = blockIdx.x;
    const int tid = threadIdx.x;
    const int w   = tid >> 6, lane = tid & 63;

    __shared__ double s_sx[4], s_sy[4];
    __shared__ unsigned s_c[4];

    // per-bin min over all slices (thread tid owns bin tid; coalesced reads)
    float acc = ACCINIT;
    const float* bp = binpart + (size_t)nn * CPS * P + tid;
#pragma unroll 4
    for (int c = 0; c < CPS; ++c) acc = fminf(acc, bp[(size_t)c * P]);
    double sx = (double)acc;

    double sy = 0.0; unsigned cnt = 0;
    for (int i = tid; i < CPS; i += BLOCK) {
        sy  += ysum_part[nn * CPS + i];
        cnt += ycnt_part[nn * CPS + i];
    }
    for (int off = 32; off > 0; off >>= 1) {
        sx  += __shfl_down(sx, off, 64);
        sy  += __shfl_down(sy, off, 64);
        cnt += __shfl_down(cnt, off, 64);
    }
    if (lane == 0) { s_sx[w] = sx; s_sy[w] = sy; s_c[w] = cnt; }
    __syncthreads();
    if (tid == 0) {
        double SX = (s_sx[0] + s_sx[1] + s_sx[2] + s_sx[3]) / (double)P;
        double SY = s_sy[0] + s_sy[1] + s_sy[2] + s_sy[3];
        unsigned CC = s_c[0] + s_c[1] + s_c[2] + s_c[3];
        res[nn] = SX + SY / (double)CC;
    }
}

__global__ void chamfer_final(const double* __restrict__ res, int N,
                              float* __restrict__ out) {
    if (threadIdx.x == 0) {
        double tot = 0.0;
        for (int k = 0; k < N; ++k) tot += res[k];
        out[0] = (float)(tot / (double)N);
    }
}

extern "C" void kernel_launch(void* const* d_in, const int* in_sizes, int n_in,
                              void* d_out, int out_size, void* d_ws, size_t ws_size,
                              hipStream_t stream) {
    const float* bins = (const float*)d_in[0];
    const float* tgt  = (const float*)d_in[1];
    float* out = (float*)d_out;

    const int N = in_sizes[0] / (P + 1);      // 8
    const int M = in_sizes[1] / N;            // 65536
    const int C = (M + CHUNK - 1) / CHUNK;    // 128 chunks per sample

    // pick CPS (slices per sample) so the partial buffers fit in ws
    int CPS = C;
    size_t o_res, o_ys, o_yc, o_bp, need;
    for (;;) {
        o_res = 0;
        o_ys  = ((size_t)N * 8 + 63) / 64 * 64;
        o_yc  = o_ys + (size_t)N * CPS * 8;
        o_bp  = ((o_yc + (size_t)N * CPS * 4 + 63) / 64) * 64;
        need  = o_bp + (size_t)N * CPS * P * 4;
        if (need <= ws_size || CPS == 1) break;
        CPS >>= 1;
    }

    char* ws = (char*)d_ws;
    double*   res     = (double*)(ws + o_res);
    double*   ysum_p  = (double*)(ws + o_ys);
    unsigned* ycnt_p  = (unsigned*)(ws + o_yc);
    float*    binpart = (float*)(ws + o_bp);

    hipLaunchKernelGGL(chamfer_partial, dim3(CPS, N), dim3(BLOCK), 0, stream,
                       bins, tgt, M, C, CPS, ysum_p, ycnt_p, binpart);
    hipLaunchKernelGGL(chamfer_reduce, dim3(N), dim3(BLOCK), 0, stream,
                       ysum_p, ycnt_p, binpart, CPS, res);
    hipLaunchKernelGGL(chamfer_final, dim3(1), dim3(64), 0, stream,
                       res, N, out);
}